// Round 1
// baseline (165.348 us; speedup 1.0000x reference)
//
#include <hip/hip_runtime.h>

typedef __attribute__((ext_vector_type(8))) __bf16 bf16x8;
typedef __attribute__((ext_vector_type(4))) float f32x4;

#define DEVI static __device__ __forceinline__

DEVI unsigned short f2bf(float f) {
  unsigned int u = __float_as_uint(f);
  u += 0x7fffu + ((u >> 16) & 1u);
  return (unsigned short)(u >> 16);
}
DEVI float bf2f(unsigned short s) {
  return __uint_as_float(((unsigned int)s) << 16);
}

union Frag {
  bf16x8 v;
  unsigned short h[8];
  unsigned int w[4];
};

typedef __attribute__((address_space(1))) const void gv_t;
typedef __attribute__((address_space(3))) void sv_t;
#define GLOAD_LDS16(g, l) __builtin_amdgcn_global_load_lds((gv_t*)(g), (sv_t*)(l), 16, 0, 0)

// ---------------------------------------------------------------------------
// Convert fp32 -> bf16: x (first 512 rows per batch, 8192x1024) and 4 weights
// ---------------------------------------------------------------------------
__global__ __launch_bounds__(256) void k_convert(
    const float* __restrict__ x, const float* __restrict__ wq,
    const float* __restrict__ wk, const float* __restrict__ wv,
    const float* __restrict__ pw,
    unsigned short* __restrict__ xb, unsigned short* __restrict__ wb)
{
  int t = blockIdx.x * 256 + threadIdx.x;
  const float* src;
  unsigned short* dst;
  if (t < 1048576) {
    long e0 = (long)t << 3;
    int m = (int)(e0 >> 10), cc = (int)(e0 & 1023);
    int b = m >> 9, i = m & 511;
    src = x + (((long)(b << 10) + i) << 10) + cc;
    dst = xb + ((long)m << 10) + cc;
  } else {
    long e0 = (long)(t - 1048576) << 3;
    int mat = (int)(e0 >> 20);
    long off = e0 & 1048575;
    const float* s = (mat == 0) ? wq : (mat == 1) ? wk : (mat == 2) ? wv : pw;
    src = s + off;
    dst = wb + e0;
  }
  float4 a = *(const float4*)src;
  float4 b4 = *(const float4*)(src + 4);
  uint4 o;
  o.x = f2bf(a.x)  | ((unsigned)f2bf(a.y)  << 16);
  o.y = f2bf(a.z)  | ((unsigned)f2bf(a.w)  << 16);
  o.z = f2bf(b4.x) | ((unsigned)f2bf(b4.y) << 16);
  o.w = f2bf(b4.z) | ((unsigned)f2bf(b4.w) << 16);
  *(uint4*)dst = o;
}

// ---------------------------------------------------------------------------
// Static iRPE 'euc' bucket table, 512x512, f64 math to match numpy rounding
// ---------------------------------------------------------------------------
__global__ __launch_bounds__(256) void k_bucket(unsigned char* __restrict__ bkt)
{
  int t = blockIdx.x * 256 + threadIdx.x;   // 0..262143
  int i = t >> 9, j = t & 511;
  int ir = i / 23, ic = i - ir * 23;
  int jr = j / 23, jc = j - jr * 23;
  int dy = ir - jr, dx = ic - jc;
  double dis = rint(sqrt((double)(dy * dy + dx * dx)));
  int v;
  if (dis <= 1.9) {
    v = (int)rint(dis);
  } else {
    double far = rint(1.9 + log(dis / 1.9) * (1.9 / log(8.0)));
    v = (int)fmin(far, 3.8);
  }
  bkt[t] = (unsigned char)v;
}

// ---------------------------------------------------------------------------
// bf16 NT GEMM: C[m][n] = sum_k A[m][k]*B[n][k], M=8192, K=1024
// 128x128 tile, BK=32, 256 thr (4 waves, 2x2), global_load_lds staging.
// MODE 0: N=3072 (wq|wk|wv) -> scatter to qh/kh (head-major) and vt (transposed)
// MODE 1: N=1024 (proj)     -> fp32 out + bias
// ---------------------------------------------------------------------------
template<int MODE>
__global__ __launch_bounds__(256) void k_gemm(
    const unsigned short* __restrict__ A,
    const unsigned short* __restrict__ Bw,
    unsigned short* __restrict__ qh, unsigned short* __restrict__ kh,
    unsigned short* __restrict__ vt,
    float* __restrict__ out, const float* __restrict__ bias)
{
  __shared__ unsigned short sA[128 * 32];
  __shared__ unsigned short sB[128 * 32];
  const int tid = threadIdx.x;
  const int tileN = blockIdx.x, tileM = blockIdx.y;
  const int w = tid >> 6, lane = tid & 63;
  const int g = lane >> 4, c = lane & 15;
  const int wm = w >> 1, wn = w & 1;

  f32x4 acc[4][4] = {};

  const unsigned short* ga = A  + ((long)tileM * 128 + (tid >> 2)) * 1024 + (tid & 3) * 8;
  const unsigned short* gb = Bw + ((long)tileN * 128 + (tid >> 2)) * 1024 + (tid & 3) * 8;
  char* la = (char*)sA + tid * 16;
  char* lb = (char*)sB + tid * 16;

  for (int kt = 0; kt < 32; ++kt) {
    __syncthreads();
    const unsigned short* gak = ga + kt * 32;
    const unsigned short* gbk = gb + kt * 32;
    GLOAD_LDS16(gak,              la);
    GLOAD_LDS16(gak + 64 * 1024,  la + 4096);
    GLOAD_LDS16(gbk,              lb);
    GLOAD_LDS16(gbk + 64 * 1024,  lb + 4096);
    __syncthreads();

    bf16x8 af[4], bf[4];
#pragma unroll
    for (int mi = 0; mi < 4; ++mi)
      af[mi] = *(const bf16x8*)(sA + (wm * 64 + mi * 16 + c) * 32 + g * 8);
#pragma unroll
    for (int ni = 0; ni < 4; ++ni)
      bf[ni] = *(const bf16x8*)(sB + (wn * 64 + ni * 16 + c) * 32 + g * 8);
#pragma unroll
    for (int mi = 0; mi < 4; ++mi)
#pragma unroll
      for (int ni = 0; ni < 4; ++ni)
        acc[mi][ni] = __builtin_amdgcn_mfma_f32_16x16x32_bf16(af[mi], bf[ni], acc[mi][ni], 0, 0, 0);
  }

  const int m0 = tileM * 128 + wm * 64;
  const int n0 = tileN * 128 + wn * 64;

  if (MODE == 0) {
#pragma unroll
    for (int mi = 0; mi < 4; ++mi) {
      int mrow = m0 + mi * 16 + g * 4;
      int b = mrow >> 9, i = mrow & 511;
#pragma unroll
      for (int ni = 0; ni < 4; ++ni) {
        int n = n0 + ni * 16 + c;
        int mat = n >> 10;
        int cc = n & 1023;
        int h = cc >> 6, d = cc & 63;
        long bh = (long)(b * 16 + h);
        if (mat == 2) {
          unsigned int w0 = f2bf(acc[mi][ni][0]) | ((unsigned)f2bf(acc[mi][ni][1]) << 16);
          unsigned int w1 = f2bf(acc[mi][ni][2]) | ((unsigned)f2bf(acc[mi][ni][3]) << 16);
          *(uint2*)(vt + (bh * 64 + d) * 512 + i) = make_uint2(w0, w1);
        } else {
          unsigned short* dst = (mat == 0 ? qh : kh) + (bh * 512 + i) * 64 + d;
#pragma unroll
          for (int r = 0; r < 4; ++r)
            dst[(long)r * 64] = f2bf(acc[mi][ni][r]);
        }
      }
    }
  } else {
#pragma unroll
    for (int mi = 0; mi < 4; ++mi) {
      int mrow = m0 + mi * 16 + g * 4;
#pragma unroll
      for (int ni = 0; ni < 4; ++ni) {
        int n = n0 + ni * 16 + c;
        float bv = bias[n];
#pragma unroll
        for (int r = 0; r < 4; ++r)
          out[(long)(mrow + r) * 1024 + n] = acc[mi][ni][r] + bv;
      }
    }
  }
}

// ---------------------------------------------------------------------------
// Fused attention: 256 blocks (one per b,h) x 512 thr (8 waves x 64 q-rows).
// Swapped QK^T (S^T) with K-row permutation so P-fragments for PV need no
// cross-lane repack. Online softmax. O^T written back row-packed (8B stores).
// ---------------------------------------------------------------------------
__global__ __launch_bounds__(512) void k_attn(
    const unsigned short* __restrict__ qh, const unsigned short* __restrict__ kh,
    const unsigned short* __restrict__ vt, const float* __restrict__ rpe,
    const unsigned char* __restrict__ bkt, unsigned short* __restrict__ ao)
{
  __shared__ float lt_lds[512 * 9];
  const int bh = blockIdx.x;
  const int b = bh >> 4, h = bh & 15;
  const int w = threadIdx.x >> 6, lane = threadIdx.x & 63;
  const int g = lane >> 4, c = lane & 15;
  const int qbase = w * 64;
  const unsigned short* Q = qh + (long)bh * 512 * 64;
  const unsigned short* K = kh + (long)bh * 512 * 64;
  const unsigned short* V = vt + (long)bh * 64 * 512;

  // --- load Q fragments (persist) ---
  Frag qu[4][2];
#pragma unroll
  for (int it = 0; it < 4; ++it)
#pragma unroll
    for (int kk = 0; kk < 2; ++kk)
      qu[it][kk].v = *(const bf16x8*)(Q + (qbase + it * 16 + c) * 64 + kk * 32 + g * 8);

  // --- lt[i][n] = sum_d q[i][d] * rpe[d][n], per-lane partial over 16 d's ---
  float lt[4][7] = {};
#pragma unroll
  for (int kk = 0; kk < 2; ++kk)
#pragma unroll
    for (int tt = 0; tt < 8; ++tt) {
      int d = kk * 32 + g * 8 + tt;
      const float* rr = rpe + d * 7;
      float r0 = rr[0], r1 = rr[1], r2 = rr[2], r3 = rr[3], r4 = rr[4], r5 = rr[5], r6 = rr[6];
#pragma unroll
      for (int it = 0; it < 4; ++it) {
        float qv = bf2f(qu[it][kk].h[tt]);
        lt[it][0] += qv * r0; lt[it][1] += qv * r1; lt[it][2] += qv * r2;
        lt[it][3] += qv * r3; lt[it][4] += qv * r4; lt[it][5] += qv * r5;
        lt[it][6] += qv * r6;
      }
    }
#pragma unroll
  for (int it = 0; it < 4; ++it)
#pragma unroll
    for (int n = 0; n < 7; ++n) {
      float v = lt[it][n];
      v += __shfl_xor(v, 16);
      v += __shfl_xor(v, 32);
      if (g == 0) lt_lds[(qbase + it * 16 + c) * 9 + n] = v;
    }
  // wave-local write->read: no barrier needed

  f32x4 oacc[4][4] = {};          // [dt][it]
  float mrun[4] = {-1e30f, -1e30f, -1e30f, -1e30f};
  float lp[4] = {0.f, 0.f, 0.f, 0.f};

  for (int jb = 0; jb < 512; jb += 32) {
    // K fragments with row permutation sigma(jt,m) = (m>>2)*8 + jt*4 + (m&3)
    const int jp0 = jb + (c >> 2) * 8 + (c & 3);
    Frag kf[2][2];
#pragma unroll
    for (int jt = 0; jt < 2; ++jt)
#pragma unroll
      for (int kk = 0; kk < 2; ++kk)
        kf[jt][kk].v = *(const bf16x8*)(K + (jp0 + jt * 4) * 64 + kk * 32 + g * 8);

    f32x4 s[2][4];
#pragma unroll
    for (int jt = 0; jt < 2; ++jt)
#pragma unroll
      for (int it = 0; it < 4; ++it) {
        f32x4 z = {0.f, 0.f, 0.f, 0.f};
        z = __builtin_amdgcn_mfma_f32_16x16x32_bf16(kf[jt][0].v, qu[it][0].v, z, 0, 0, 0);
        s[jt][it] = __builtin_amdgcn_mfma_f32_16x16x32_bf16(kf[jt][1].v, qu[it][1].v, z, 0, 0, 0);
      }

    Frag pfr[4];
#pragma unroll
    for (int it = 0; it < 4; ++it) {
      int irow = qbase + it * 16 + c;
      float sv[8];
#pragma unroll
      for (int jt = 0; jt < 2; ++jt) {
        unsigned int bb = *(const unsigned int*)(bkt + (long)irow * 512 + jb + g * 8 + jt * 4);
#pragma unroll
        for (int r = 0; r < 4; ++r) {
          int bno = (bb >> (8 * r)) & 255;
          float bias = lt_lds[irow * 9 + bno];
          sv[jt * 4 + r] = s[jt][it][r] * 0.125f + bias;
        }
      }
      float pm = sv[0];
#pragma unroll
      for (int t = 1; t < 8; ++t) pm = fmaxf(pm, sv[t]);
      pm = fmaxf(pm, __shfl_xor(pm, 16));
      pm = fmaxf(pm, __shfl_xor(pm, 32));
      float mnew = fmaxf(mrun[it], pm);
      float fsc = __expf(mrun[it] - mnew);
      mrun[it] = mnew;
      lp[it] *= fsc;
#pragma unroll
      for (int dt = 0; dt < 4; ++dt) oacc[dt][it] = oacc[dt][it] * fsc;
      float psum = 0.f;
#pragma unroll
      for (int t = 0; t < 8; ++t) {
        float e = __expf(sv[t] - mnew);
        psum += e;
        pfr[it].h[t] = f2bf(e);
      }
      lp[it] += psum;
    }

    bf16x8 vf[4];
#pragma unroll
    for (int dt = 0; dt < 4; ++dt)
      vf[dt] = *(const bf16x8*)(V + (dt * 16 + c) * 512 + jb + g * 8);

#pragma unroll
    for (int dt = 0; dt < 4; ++dt)
#pragma unroll
      for (int it = 0; it < 4; ++it)
        oacc[dt][it] = __builtin_amdgcn_mfma_f32_16x16x32_bf16(vf[dt], pfr[it].v, oacc[dt][it], 0, 0, 0);
  }

  float li[4];
#pragma unroll
  for (int it = 0; it < 4; ++it) {
    float v = lp[it];
    v += __shfl_xor(v, 16);
    v += __shfl_xor(v, 32);
    li[it] = 1.0f / v;
  }
#pragma unroll
  for (int dt = 0; dt < 4; ++dt)
#pragma unroll
    for (int it = 0; it < 4; ++it) {
      int irow = qbase + it * 16 + c;
      int d0 = dt * 16 + g * 4;
      unsigned int w0 = f2bf(oacc[dt][it][0] * li[it]) | ((unsigned)f2bf(oacc[dt][it][1] * li[it]) << 16);
      unsigned int w1 = f2bf(oacc[dt][it][2] * li[it]) | ((unsigned)f2bf(oacc[dt][it][3] * li[it]) << 16);
      *(uint2*)(ao + ((long)(b * 512 + irow)) * 1024 + h * 64 + d0) = make_uint2(w0, w1);
    }
}

// ---------------------------------------------------------------------------
extern "C" void kernel_launch(void* const* d_in, const int* in_sizes, int n_in,
                              void* d_out, int out_size, void* d_ws, size_t ws_size,
                              hipStream_t stream) {
  const float* x   = (const float*)d_in[0];
  const float* wq  = (const float*)d_in[1];
  const float* wk  = (const float*)d_in[2];
  const float* wv  = (const float*)d_in[3];
  const float* rpe = (const float*)d_in[4];
  const float* pw  = (const float*)d_in[5];
  const float* pb  = (const float*)d_in[6];
  float* out = (float*)d_out;

  char* ws = (char*)d_ws;
  unsigned short* xb  = (unsigned short*)(ws);                 // 8192x1024 bf16 (16 MB)
  unsigned short* wb  = (unsigned short*)(ws + 16777216);      // 4x1024x1024 bf16 (8 MB)
  unsigned short* qhp = (unsigned short*)(ws + 25165824);      // [bh][512][64]
  unsigned short* khp = (unsigned short*)(ws + 41943040);      // [bh][512][64]
  unsigned short* vtp = (unsigned short*)(ws + 58720256);      // [bh][64][512]
  unsigned char*  bkt = (unsigned char*)(ws + 75497472);       // 512x512
  unsigned short* aop = xb;                                    // alias: xb dead after QKV gemm

  k_convert<<<dim3(6144), dim3(256), 0, stream>>>(x, wq, wk, wv, pw, xb, wb);
  k_bucket<<<dim3(1024), dim3(256), 0, stream>>>(bkt);
  k_gemm<0><<<dim3(24, 64), dim3(256), 0, stream>>>(xb, wb, qhp, khp, vtp, nullptr, nullptr);
  k_attn<<<dim3(256), dim3(512), 0, stream>>>(qhp, khp, vtp, rpe, bkt, aop);
  k_gemm<1><<<dim3(8, 64), dim3(256), 0, stream>>>(aop, wb + 3 * 1048576, nullptr, nullptr, nullptr, out, pb);
}